// Round 2
// baseline (420.760 us; speedup 1.0000x reference)
//
#include <hip/hip_runtime.h>

// BD field layout constants (match the reference)
#define D 256
#define OUT_LO    96
#define OUT_HI    112
#define TPW 4   // tokens per wave: 4 independent 16B/lane loads in flight -> 4x MLP

// One wave (64 lanes) handles TPW consecutive tokens. Lane i owns float4
// covering elements [4i, 4i+4) of each token. All TPW loads issue before any
// dependent shuffle work; the TPW decode chains are independent and interleave.
__global__ __launch_bounds__(256) void alu_shift_kernel(
    const float* __restrict__ x, float* __restrict__ out, int n_tokens)
{
    const int lane = threadIdx.x & 63;
    const int wid  = blockIdx.x * (blockDim.x >> 6) + (threadIdx.x >> 6);
    const int token0 = wid * TPW;
    if (token0 >= n_tokens) return;

    const float4* __restrict__ xin = (const float4*)x   + (size_t)token0 * (D / 4) + lane;
    float4*       __restrict__ xo  = (float4*)out       + (size_t)token0 * (D / 4) + lane;

    // Phase 1: issue all loads (independent -> all outstanding simultaneously)
    float4 v[TPW];
#pragma unroll
    for (int t = 0; t < TPW; ++t)
        v[t] = xin[(size_t)t * (D / 4)];

    // Phase 2: per-lane masks (VALU only, overlaps load latency of later tokens)
    unsigned m[TPW], fl[TPW];
#pragma unroll
    for (int t = 0; t < TPW; ++t) {
        m[t]  = (unsigned)(v[t].x > 0.5f)
              | ((unsigned)(v[t].y > 0.5f) << 1)
              | ((unsigned)(v[t].z > 0.5f) << 2)
              | ((unsigned)(v[t].w > 0.5f) << 3);
        // Lane 0 holds elements 0..3: mark (>=0.5!), shl (>0.5), shr (>0.5)
        fl[t] = (unsigned)(v[t].x >= 0.5f)
              | ((unsigned)(v[t].y > 0.5f) << 1)
              | ((unsigned)(v[t].z > 0.5f) << 2);
    }

    // Phase 3: decode + patch + store, TPW independent chains
#pragma unroll
    for (int t = 0; t < TPW; ++t) {
        const unsigned flags = __shfl(fl[t], 0);

        // ALU_LO = elems 16..31 (lanes 4..7), ALU_HI = 32..47 (8..11), SHIFT = 48..63 (12..15)
        const unsigned mlo = __shfl(m[t], 4)  | (__shfl(m[t], 5)  << 4)
                           | (__shfl(m[t], 6)  << 8) | (__shfl(m[t], 7)  << 12);
        const unsigned mhi = __shfl(m[t], 8)  | (__shfl(m[t], 9)  << 4)
                           | (__shfl(m[t], 10) << 8) | (__shfl(m[t], 11) << 12);
        const unsigned msh = __shfl(m[t], 12) | (__shfl(m[t], 13) << 4)
                           | (__shfl(m[t], 14) << 8) | (__shfl(m[t], 15) << 12);

        // first-hot: index of first set bit; 0 if none (matches argmax of all-false)
        const int lo    = mlo ? (__ffs((int)mlo) - 1) : 0;
        const int hi    = mhi ? (__ffs((int)mhi) - 1) : 0;
        const int shift = msh ? (__ffs((int)msh) - 1) : 0;

        const bool mark = (flags & 1u) != 0u;
        const bool shl  = (flags & 2u) != 0u;
        const bool shr  = (!shl) && ((flags & 4u) != 0u);
        const bool active = mark && (shl || shr);

        const int value = hi * 16 + lo;
        int res = shl ? ((value << shift) & 255) : (value >> shift);
        res = active ? res : 0;

        const int tlo = OUT_LO + (res & 15);   // 96..111
        const int thi = OUT_HI + (res >> 4);   // 112..127 (disjoint from tlo)

        if (active) {                          // wave-uniform branch
            const int base = lane << 2;
            v[t].x += (base + 0 == tlo || base + 0 == thi) ? 2.0f : 0.0f;
            v[t].y += (base + 1 == tlo || base + 1 == thi) ? 2.0f : 0.0f;
            v[t].z += (base + 2 == tlo || base + 2 == thi) ? 2.0f : 0.0f;
            v[t].w += (base + 3 == tlo || base + 3 == thi) ? 2.0f : 0.0f;
        }

        xo[(size_t)t * (D / 4)] = v[t];
    }
}

extern "C" void kernel_launch(void* const* d_in, const int* in_sizes, int n_in,
                              void* d_out, int out_size, void* d_ws, size_t ws_size,
                              hipStream_t stream)
{
    (void)n_in; (void)out_size; (void)d_ws; (void)ws_size;

    const float* x = (const float*)d_in[0];
    float* out = (float*)d_out;

    const int n_tokens = in_sizes[0] / D;                 // B*S = 262144
    const int threads = 256;                              // 4 waves/block
    const int tokens_per_block = (threads / 64) * TPW;    // 16
    const int blocks = (n_tokens + tokens_per_block - 1) / tokens_per_block;

    alu_shift_kernel<<<blocks, threads, 0, stream>>>(x, out, n_tokens);
}